// Round 6
// baseline (1038.980 us; speedup 1.0000x reference)
//
#include <hip/hip_runtime.h>

// S=8, N=4096, F_IN=F_OUT=128
constexpr int N  = 4096;
constexpr int F  = 128;
constexpr int S  = 8;
constexpr int BM = 64;              // rows per block (kernel1)
constexpr int KSPLIT = 8;
constexpr int KRANGE = N / KSPLIT;  // 512
constexpr int BK = 32;              // k-chunk
constexpr int NCH = KRANGE / BK;    // 16 chunks per block
constexpr int NT = 256;

typedef float f4 __attribute__((ext_vector_type(4)));

// Barrier that waits only on LDS ops; global loads stay in flight unless we
// explicitly drain vmcnt first.
__device__ __forceinline__ void bar_sync() {
  asm volatile("s_waitcnt lgkmcnt(0)" ::: "memory");
  __builtin_amdgcn_s_barrier();
  asm volatile("" ::: "memory");
}

__device__ __forceinline__ void vm_drain() {
  asm volatile("s_waitcnt vmcnt(0)" ::: "memory");
}

// async global->LDS, 16B per lane; LDS dest = wave-uniform base + lane*16.
__device__ __forceinline__ void gload_lds16(const float* g, float* l) {
  __builtin_amdgcn_global_load_lds(
      (const __attribute__((address_space(1))) void*)g,
      (__attribute__((address_space(3))) void*)l, 16, 0, 0);
}

// ---------------- kernel 1: q-gen + q@x partial, k-split ----------------
// USE_WS: write partials to ws[ks][N][F] with plain stores.
// else  : atomicAdd into out (pre-zeroed).
template <bool USE_WS>
__global__ __launch_bounds__(NT, 2) void ggd_diffuse(
    const float* __restrict__ theta,
    const float* __restrict__ Ts,     // [S][N][N]
    const float* __restrict__ x,      // [N][F]
    const float* __restrict__ a,      // [N][N]
    float* __restrict__ dst)          // ws [KSPLIT][N][F]  or  out [N][F]
{
  __shared__ float q_lds[2][BM][BK];  // 16 KB double-buffered, linear
  __shared__ float x_lds[2][BK * F];  // 32 KB double-buffered, linear

  const int t  = threadIdx.x;
  const int rb = blockIdx.x >> 3;     // 0..63  row block
  const int ks = blockIdx.x & 7;      // 0..7   k-split (~XCD-local x slice)
  const int n0 = rb * BM;
  const int k0 = ks * KRANGE;

  float th[S];
#pragma unroll
  for (int s = 0; s < S; ++s) th[s] = theta[s];

  const int wave = t >> 6, lane = t & 63;

  // producer mapping: per half h (h=0: rows 0..31, h=1: rows 32..63)
  // thread covers row pr+32h, cols pk..pk+3; wave writes 1KB linear.
  const int pr = t >> 3;              // 0..31
  const int pk = (t & 7) * 4;         // 0,4,...,28
  const size_t prowOff = (size_t)(n0 + pr) * N + k0 + pk;
  const size_t halfOff = (size_t)32 * N;
  const size_t slice   = (size_t)N * N;

  // consumer mapping: rows rg*8..rg*8+7, feats fg*4..fg*4+3
  const int rg = t >> 5;              // 0..7
  const int fg = t & 31;              // 0..31

  f4 acc[8];
#pragma unroll
  for (int r = 0; r < 8; ++r) acc[r] = (f4)(0.f);

  // staging registers, reused by both halves: 9 f4 = 36 VGPR
  f4 sa;
  f4 st[S];

  auto load_Ta = [&](int c, int h) {
    const size_t off = prowOff + (size_t)h * halfOff + (size_t)c * BK;
    sa = *(const f4*)(a + off);
#pragma unroll
    for (int s = 0; s < S; ++s)
      st[s] = *(const f4*)(Ts + (size_t)s * slice + off);
  };

  auto commit_q = [&](int buf, int h) {
    f4 q;
#pragma unroll
    for (int j = 0; j < 4; ++j) {
      float sum = th[0] * st[0][j];
#pragma unroll
      for (int s = 1; s < S; ++s) sum = fmaf(th[s], st[s][j], sum);
      q[j] = sa[j] * sum;
    }
    *(f4*)&q_lds[buf][pr + 32 * h][pk] = q;
  };

  auto stage_x = [&](int c, int buf) {
    const float* xg = x + (size_t)(k0 + c * BK) * F;
#pragma unroll
    for (int i = 0; i < 4; ++i) {
      const int seg = (wave * 4 + i) * 256;   // wave-uniform LDS base
      gload_lds16(xg + seg + lane * 4, &x_lds[buf][seg]);
    }
  };

  // compute 4 k4-iterations [k4lo, k4lo+4) of chunk in buf, pure LDS
  auto compute_half = [&](int buf, int k4lo) {
    const float* qb = &q_lds[buf][rg * 8][0];
    const float* xb = &x_lds[buf][0] + fg * 4;
#pragma unroll
    for (int k4 = k4lo; k4 < k4lo + 4; ++k4) {
      f4 xv[4];
#pragma unroll
      for (int j = 0; j < 4; ++j)
        xv[j] = *(const f4*)(xb + (size_t)(k4 * 4 + j) * F);
#pragma unroll
      for (int rr = 0; rr < 8; ++rr) {
        f4 qv = *(const f4*)(qb + rr * BK + k4 * 4);
#pragma unroll
        for (int j = 0; j < 4; ++j)
#pragma unroll
          for (int e = 0; e < 4; ++e)
            acc[rr][e] = fmaf(qv[j], xv[j][e], acc[rr][e]);
      }
    }
  };

  // prologue: build buffer 0 (latency exposed once)
  load_Ta(0, 0);
  stage_x(0, 0);
  commit_q(0, 0);
  load_Ta(0, 1);
  commit_q(0, 1);
  vm_drain();
  bar_sync();

  for (int c = 0; c < NCH; ++c) {
    const int buf = c & 1;
    const bool more = (c + 1 < NCH);

    if (more) {
      load_Ta(c + 1, 0);          // 9 f4 -> regs
      stage_x(c + 1, buf ^ 1);    // 4 async gload_lds, zero VGPR
    }
    compute_half(buf, 0);          // overlaps the loads above
    if (more) {
      commit_q(buf ^ 1, 0);        // waits half-0 T/a loads only
      load_Ta(c + 1, 1);           // issue half-1 loads
    }
    compute_half(buf, 4);          // overlaps half-1 loads
    if (more) commit_q(buf ^ 1, 1);
    vm_drain();                    // x[c+1] resident in LDS
    bar_sync();                    // publish q[c+1] + x[c+1]
  }

  // write partials
#pragma unroll
  for (int rr = 0; rr < 8; ++rr) {
    const size_t row = (size_t)(n0 + rg * 8 + rr);
    if (USE_WS) {
      float* op = dst + ((size_t)ks * N + row) * F + fg * 4;
      *(f4*)op = acc[rr];
    } else {
      float* op = dst + row * F + fg * 4;
#pragma unroll
      for (int e = 0; e < 4; ++e) atomicAdd(op + e, acc[rr][e]);
    }
  }
}

// ---------------- kernel 2: (reduce) + PReLU + FC ----------------
template <bool USE_WS>
__global__ __launch_bounds__(256, 2) void ggd_fc(
    const float* __restrict__ W,      // [F][F] row-major [fo][fi]
    const float* __restrict__ bfc,    // [F]
    const float* __restrict__ alpha,  // [F]
    const float* __restrict__ src,    // ws [KSPLIT][N][F] or out [N][F]
    float* __restrict__ out)          // [N][F]
{
  __shared__ float p_lds[16 * F];     // 8 KB
  const int t  = threadIdx.x;
  const int n0 = blockIdx.x * 16;

  // gather 16 rows (+ reduce over ksplit) + PReLU -> LDS
  {
    const int lr = t >> 4, c8 = (t & 15) * 8;
    f4 v0, v1;
    if (USE_WS) {
      v0 = (f4)(0.f); v1 = (f4)(0.f);
#pragma unroll
      for (int ks = 0; ks < KSPLIT; ++ks) {
        const float* sp = src + ((size_t)ks * N + n0 + lr) * F + c8;
        v0 += *(const f4*)(sp);
        v1 += *(const f4*)(sp + 4);
      }
    } else {
      const float* ip = src + (size_t)(n0 + lr) * F + c8;
      v0 = *(const f4*)(ip);
      v1 = *(const f4*)(ip + 4);
    }
    f4 a0 = *(const f4*)(alpha + c8);
    f4 a1 = *(const f4*)(alpha + c8 + 4);
#pragma unroll
    for (int j = 0; j < 4; ++j) {
      v0[j] = v0[j] >= 0.f ? v0[j] : a0[j] * v0[j];
      v1[j] = v1[j] >= 0.f ? v1[j] : a1[j] * v1[j];
    }
    *(f4*)&p_lds[lr * F + c8]     = v0;
    *(f4*)&p_lds[lr * F + c8 + 4] = v1;
  }
  __syncthreads();

  // FC: thread -> rows {r2, r2+8}, outputs fo0..fo0+3; W streamed from L2
  const int r2  = t >> 5;             // 0..7
  const int fo0 = (t & 31) * 4;
  f4 accA = *(const f4*)(bfc + fo0);
  f4 accB = accA;
#pragma unroll 4
  for (int fi4 = 0; fi4 < F / 4; ++fi4) {
    f4 pA = *(const f4*)&p_lds[r2 * F + fi4 * 4];
    f4 pB = *(const f4*)&p_lds[(r2 + 8) * F + fi4 * 4];
#pragma unroll
    for (int e = 0; e < 4; ++e) {
      f4 wv = *(const f4*)(W + (size_t)(fo0 + e) * F + fi4 * 4);
      accA[e] = fmaf(pA[0], wv[0], fmaf(pA[1], wv[1],
                fmaf(pA[2], wv[2], fmaf(pA[3], wv[3], accA[e]))));
      accB[e] = fmaf(pB[0], wv[0], fmaf(pB[1], wv[1],
                fmaf(pB[2], wv[2], fmaf(pB[3], wv[3], accB[e]))));
    }
  }
  *(f4*)(out + (size_t)(n0 + r2) * F + fo0)     = accA;
  *(f4*)(out + (size_t)(n0 + r2 + 8) * F + fo0) = accB;
}

extern "C" void kernel_launch(void* const* d_in, const int* in_sizes, int n_in,
                              void* d_out, int out_size, void* d_ws, size_t ws_size,
                              hipStream_t stream) {
  const float* theta = (const float*)d_in[0];
  const float* Ts    = (const float*)d_in[1];
  const float* x     = (const float*)d_in[2];
  const float* a     = (const float*)d_in[3];
  const float* W     = (const float*)d_in[4];
  const float* bfc   = (const float*)d_in[5];
  const float* alpha = (const float*)d_in[6];
  float* out = (float*)d_out;

  const size_t ws_need = (size_t)KSPLIT * N * F * sizeof(float);
  if (ws_size >= ws_need && d_ws != nullptr) {
    float* ws = (float*)d_ws;
    ggd_diffuse<true><<<dim3((N / BM) * KSPLIT), dim3(NT), 0, stream>>>(
        theta, Ts, x, a, ws);
    ggd_fc<true><<<dim3(N / 16), dim3(256), 0, stream>>>(
        W, bfc, alpha, ws, out);
  } else {
    hipMemsetAsync(out, 0, (size_t)out_size * sizeof(float), stream);
    ggd_diffuse<false><<<dim3((N / BM) * KSPLIT), dim3(NT), 0, stream>>>(
        theta, Ts, x, a, out);
    ggd_fc<false><<<dim3(N / 16), dim3(256), 0, stream>>>(
        W, bfc, alpha, out, out);
  }
}

// Round 7
// 147.394 us; speedup vs baseline: 7.0490x; 7.0490x over previous
//
#include <hip/hip_runtime.h>

// S=8, N=4096, F_IN=F_OUT=128
constexpr int N  = 4096;
constexpr int F  = 128;
constexpr int S  = 8;
constexpr int BM = 32;              // rows per block (kernel1)
constexpr int KSPLIT = 8;
constexpr int KRANGE = N / KSPLIT;  // 512
constexpr int BK = 32;              // k-chunk
constexpr int NCH = KRANGE / BK;    // 16 chunks per block
constexpr int NT = 256;

typedef float f4 __attribute__((ext_vector_type(4)));

// Barrier that waits only on LDS ops.
__device__ __forceinline__ void bar_sync() {
  asm volatile("s_waitcnt lgkmcnt(0)" ::: "memory");
  __builtin_amdgcn_s_barrier();
  asm volatile("" ::: "memory");
}

__device__ __forceinline__ void vm_drain() {
  asm volatile("s_waitcnt vmcnt(0)" ::: "memory");
}

// async global->LDS, 16B per lane; LDS dest = wave-uniform base + lane*16,
// global src is per-lane.
__device__ __forceinline__ void gload_lds16(const float* g, float* l) {
  __builtin_amdgcn_global_load_lds(
      (const __attribute__((address_space(1))) void*)g,
      (__attribute__((address_space(3))) void*)l, 16, 0, 0);
}

// ---------------- kernel 1: q-gen + q@x partial, k-split ----------------
template <bool USE_WS>
__global__ __launch_bounds__(NT, 2) void ggd_diffuse(
    const float* __restrict__ theta,
    const float* __restrict__ Ts,     // [S][N][N]
    const float* __restrict__ x,      // [N][F]
    const float* __restrict__ a,      // [N][N]
    float* __restrict__ dst)          // ws [KSPLIT][N][F]  or  out [N][F]
{
  __shared__ float rawT[S][BM][BK];   // 32 KB, single-buffered
  __shared__ float rawA[BM][BK];      //  4 KB, single-buffered
  __shared__ float x_lds[2][BK * F];  // 32 KB, double-buffered
  __shared__ float q_lds[BM][BK];     //  4 KB, single-buffered

  const int t  = threadIdx.x;
  const int rb = blockIdx.x >> 3;     // 0..127 row block
  const int ks = blockIdx.x & 7;      // 0..7   k-split (~XCD-local x slice)
  const int n0 = rb * BM;
  const int k0 = ks * KRANGE;

  float th[S];
#pragma unroll
  for (int s = 0; s < S; ++s) th[s] = theta[s];

  const int wave = t >> 6, lane = t & 63;

  // per-lane source geometry for the raw T/a gloads:
  // each 1KB instr covers 8 rows x 32 k; lane -> row lane>>3, k (lane&7)*4
  const int grow = lane >> 3;         // 0..7
  const int gcol = (lane & 7) * 4;    // 0..28
  const size_t slice = (size_t)N * N;

  // qgen mapping: thread t -> row qr, cols qk..qk+3 (one f4)
  const int qr = t >> 3;              // 0..31
  const int qk = (t & 7) * 4;

  // consumer mapping: rows rg*4..rg*4+3, feats fg*4..fg*4+3
  const int rg = t >> 5;              // 0..7
  const int fg = t & 31;              // 0..31

  f4 acc[4];
#pragma unroll
  for (int r = 0; r < 4; ++r) acc[r] = (f4)(0.f);

  // stage raw T (32 KB = 32 instrs, 8 per wave) + a (4 KB, 1 per wave)
  auto stage_raw = [&](int c) {
    const size_t cb = (size_t)(k0 + c * BK) + gcol;
#pragma unroll
    for (int j = 0; j < 8; ++j) {
      const int i = wave * 8 + j;     // 0..31
      const int s = i >> 2;           // slice
      const int q4 = i & 3;           // row quarter
      const float* src = Ts + (size_t)s * slice +
                         (size_t)(n0 + q4 * 8 + grow) * N + cb;
      gload_lds16(src, &rawT[0][0][0] + i * 256);
    }
    {
      const float* src = a + (size_t)(n0 + wave * 8 + grow) * N + cb;
      gload_lds16(src, &rawA[0][0] + wave * 256);
    }
  };

  // stage x chunk (16 KB = 16 instrs, 4 per wave)
  auto stage_x = [&](int c, int buf) {
    const float* xg = x + (size_t)(k0 + c * BK) * F;
#pragma unroll
    for (int i = 0; i < 4; ++i) {
      const int seg = (wave * 4 + i) * 256;
      gload_lds16(xg + seg + lane * 4, &x_lds[buf][seg]);
    }
  };

  // q[qr][qk..+3] = a * sum_s th[s]*T[s]  (reads rawT/rawA, writes q_lds)
  auto qgen = [&]() {
    f4 av = *(const f4*)&rawA[qr][qk];
    f4 sum;
    {
      f4 tv = *(const f4*)&rawT[0][qr][qk];
#pragma unroll
      for (int j = 0; j < 4; ++j) sum[j] = th[0] * tv[j];
    }
#pragma unroll
    for (int s = 1; s < S; ++s) {
      f4 tv = *(const f4*)&rawT[s][qr][qk];
#pragma unroll
      for (int j = 0; j < 4; ++j) sum[j] = fmaf(th[s], tv[j], sum[j]);
    }
    f4 q;
#pragma unroll
    for (int j = 0; j < 4; ++j) q[j] = av[j] * sum[j];
    *(f4*)&q_lds[qr][qk] = q;
  };

  auto compute = [&](int buf) {
    const float* qb = &q_lds[rg * 4][0];
    const float* xb = &x_lds[buf][0] + fg * 4;
#pragma unroll
    for (int k4 = 0; k4 < BK / 4; ++k4) {
      f4 xv[4];
#pragma unroll
      for (int j = 0; j < 4; ++j)
        xv[j] = *(const f4*)(xb + (size_t)(k4 * 4 + j) * F);
#pragma unroll
      for (int rr = 0; rr < 4; ++rr) {
        f4 qv = *(const f4*)(qb + rr * BK + k4 * 4);
#pragma unroll
        for (int j = 0; j < 4; ++j)
#pragma unroll
          for (int e = 0; e < 4; ++e)
            acc[rr][e] = fmaf(qv[j], xv[j][e], acc[rr][e]);
      }
    }
  };

  // prologue
  stage_raw(0);
  stage_x(0, 0);
  vm_drain();
  bar_sync();
  qgen();
  bar_sync();

  for (int c = 0; c < NCH; ++c) {
    const int buf = c & 1;
    const bool more = (c + 1 < NCH);
    if (more) {
      stage_raw(c + 1);           // raw slot is free (qgen(c) already read it)
      stage_x(c + 1, buf ^ 1);
    }
    compute(buf);                  // overlaps the gloads above
    if (more) {
      vm_drain();                  // gloads had the whole compute to land
      bar_sync();                  // all waves done with q[c]
      qgen();                      // build q[c+1] (overwrites q[c])
      bar_sync();                  // publish q[c+1] + x[c+1]
    }
  }

  // write partials
#pragma unroll
  for (int rr = 0; rr < 4; ++rr) {
    const size_t row = (size_t)(n0 + rg * 4 + rr);
    if (USE_WS) {
      float* op = dst + ((size_t)ks * N + row) * F + fg * 4;
      *(f4*)op = acc[rr];
    } else {
      float* op = dst + row * F + fg * 4;
#pragma unroll
      for (int e = 0; e < 4; ++e) atomicAdd(op + e, acc[rr][e]);
    }
  }
}

// ---------------- kernel 2: (reduce) + PReLU + FC ----------------
template <bool USE_WS>
__global__ __launch_bounds__(256, 2) void ggd_fc(
    const float* __restrict__ W,      // [F][F] row-major [fo][fi]
    const float* __restrict__ bfc,    // [F]
    const float* __restrict__ alpha,  // [F]
    const float* __restrict__ src,    // ws [KSPLIT][N][F] or out [N][F]
    float* __restrict__ out)          // [N][F]
{
  __shared__ float p_lds[16 * F];     // 8 KB
  const int t  = threadIdx.x;
  const int n0 = blockIdx.x * 16;

  // gather 16 rows (+ reduce over ksplit) + PReLU -> LDS
  {
    const int lr = t >> 4, c8 = (t & 15) * 8;
    f4 v0, v1;
    if (USE_WS) {
      v0 = (f4)(0.f); v1 = (f4)(0.f);
#pragma unroll
      for (int ks = 0; ks < KSPLIT; ++ks) {
        const float* sp = src + ((size_t)ks * N + n0 + lr) * F + c8;
        v0 += *(const f4*)(sp);
        v1 += *(const f4*)(sp + 4);
      }
    } else {
      const float* ip = src + (size_t)(n0 + lr) * F + c8;
      v0 = *(const f4*)(ip);
      v1 = *(const f4*)(ip + 4);
    }
    f4 a0 = *(const f4*)(alpha + c8);
    f4 a1 = *(const f4*)(alpha + c8 + 4);
#pragma unroll
    for (int j = 0; j < 4; ++j) {
      v0[j] = v0[j] >= 0.f ? v0[j] : a0[j] * v0[j];
      v1[j] = v1[j] >= 0.f ? v1[j] : a1[j] * v1[j];
    }
    *(f4*)&p_lds[lr * F + c8]     = v0;
    *(f4*)&p_lds[lr * F + c8 + 4] = v1;
  }
  __syncthreads();

  // FC: thread -> rows {r2, r2+8}, outputs fo0..fo0+3; W streamed from L2
  const int r2  = t >> 5;             // 0..7
  const int fo0 = (t & 31) * 4;
  f4 accA = *(const f4*)(bfc + fo0);
  f4 accB = accA;
#pragma unroll 4
  for (int fi4 = 0; fi4 < F / 4; ++fi4) {
    f4 pA = *(const f4*)&p_lds[r2 * F + fi4 * 4];
    f4 pB = *(const f4*)&p_lds[(r2 + 8) * F + fi4 * 4];
#pragma unroll
    for (int e = 0; e < 4; ++e) {
      f4 wv = *(const f4*)(W + (size_t)(fo0 + e) * F + fi4 * 4);
      accA[e] = fmaf(pA[0], wv[0], fmaf(pA[1], wv[1],
                fmaf(pA[2], wv[2], fmaf(pA[3], wv[3], accA[e]))));
      accB[e] = fmaf(pB[0], wv[0], fmaf(pB[1], wv[1],
                fmaf(pB[2], wv[2], fmaf(pB[3], wv[3], accB[e]))));
    }
  }
  *(f4*)(out + (size_t)(n0 + r2) * F + fo0)     = accA;
  *(f4*)(out + (size_t)(n0 + r2 + 8) * F + fo0) = accB;
}

extern "C" void kernel_launch(void* const* d_in, const int* in_sizes, int n_in,
                              void* d_out, int out_size, void* d_ws, size_t ws_size,
                              hipStream_t stream) {
  const float* theta = (const float*)d_in[0];
  const float* Ts    = (const float*)d_in[1];
  const float* x     = (const float*)d_in[2];
  const float* a     = (const float*)d_in[3];
  const float* W     = (const float*)d_in[4];
  const float* bfc   = (const float*)d_in[5];
  const float* alpha = (const float*)d_in[6];
  float* out = (float*)d_out;

  const size_t ws_need = (size_t)KSPLIT * N * F * sizeof(float);
  if (ws_size >= ws_need && d_ws != nullptr) {
    float* ws = (float*)d_ws;
    ggd_diffuse<true><<<dim3((N / BM) * KSPLIT), dim3(NT), 0, stream>>>(
        theta, Ts, x, a, ws);
    ggd_fc<true><<<dim3(N / 16), dim3(256), 0, stream>>>(
        W, bfc, alpha, ws, out);
  } else {
    hipMemsetAsync(out, 0, (size_t)out_size * sizeof(float), stream);
    ggd_diffuse<false><<<dim3((N / BM) * KSPLIT), dim3(NT), 0, stream>>>(
        theta, Ts, x, a, out);
    ggd_fc<false><<<dim3(N / 16), dim3(256), 0, stream>>>(
        W, bfc, alpha, out, out);
  }
}

// Round 8
// 142.578 us; speedup vs baseline: 7.2871x; 1.0338x over previous
//
#include <hip/hip_runtime.h>
#include <stdint.h>

// S=8, N=4096, F_IN=F_OUT=128
constexpr int N  = 4096;
constexpr int F  = 128;
constexpr int S  = 8;
constexpr int BM = 32;              // rows per block (kernel1)
constexpr int KSPLIT = 8;
constexpr int KRANGE = N / KSPLIT;  // 512
constexpr int BK = 32;              // k-chunk
constexpr int NCH = KRANGE / BK;    // 16 chunks per block
constexpr int NT = 256;

typedef float f4  __attribute__((ext_vector_type(4)));
typedef short bf16x8 __attribute__((ext_vector_type(8)));
typedef unsigned short us4 __attribute__((ext_vector_type(4)));

__device__ __forceinline__ unsigned short f2bf(float f) {
  union { float f; unsigned int u; } v; v.f = f;
  unsigned int u = v.u + 0x7FFFu + ((v.u >> 16) & 1u);  // RNE
  return (unsigned short)(u >> 16);
}

// Barrier that waits only on LDS ops.
__device__ __forceinline__ void bar_sync() {
  asm volatile("s_waitcnt lgkmcnt(0)" ::: "memory");
  __builtin_amdgcn_s_barrier();
  asm volatile("" ::: "memory");
}

__device__ __forceinline__ void vm_drain() {
  asm volatile("s_waitcnt vmcnt(0)" ::: "memory");
}

// async global->LDS, 16B/lane; LDS dest = wave-uniform base + lane*16.
__device__ __forceinline__ void gload_lds16(const void* g, void* l) {
  __builtin_amdgcn_global_load_lds(
      (const __attribute__((address_space(1))) void*)g,
      (__attribute__((address_space(3))) void*)l, 16, 0, 0);
}

// ---------------- kernel 0: xT[f][k] = bf16(x[k][f]) ----------------
__global__ __launch_bounds__(256, 2) void ggd_xt(
    const float* __restrict__ x, unsigned short* __restrict__ xT) {
  __shared__ float xl[64][132];       // +4 pad: conflict-free column reads
  const int t  = threadIdx.x;
  const int k0 = blockIdx.x * 64;

  {
    const int kr = t >> 2, fs = (t & 3) * 32;
    const float* src = x + (size_t)(k0 + kr) * F + fs;
#pragma unroll
    for (int i = 0; i < 8; ++i)
      *(f4*)&xl[kr][fs + i * 4] = *(const f4*)(src + i * 4);
  }
  __syncthreads();
  {
    const int f = t >> 1, kh = (t & 1) * 32;
    us4 o[8];
#pragma unroll
    for (int i = 0; i < 32; ++i)
      o[i >> 2][i & 3] = f2bf(xl[kh + i][f]);
    unsigned short* dst = xT + (size_t)f * N + k0 + kh;
#pragma unroll
    for (int j = 0; j < 8; ++j)
      *(us4*)(dst + j * 4) = o[j];
  }
}

// ---------------- kernel 1: q-gen + MFMA q@x partials ----------------
template <bool USE_WS>
__global__ __launch_bounds__(NT, 2) void ggd_diffuse(
    const float* __restrict__ theta,
    const float* __restrict__ Ts,     // [S][N][N]
    const unsigned short* __restrict__ xT,  // [F][N] bf16
    const float* __restrict__ a,      // [N][N]
    float* __restrict__ dst)          // ws [KSPLIT][N][F] or out [N][F]
{
  __shared__ float rawT[S][BM][BK];        // 32 KB single-buffered
  __shared__ float rawA[BM][BK];           //  4 KB single-buffered
  __shared__ unsigned short xt_lds[2][F][BK];  // 16 KB double-buffered (bf16)
  __shared__ unsigned short q_lds[BM][BK];     //  2 KB single-buffered (bf16)

  const int t  = threadIdx.x;
  const int rb = blockIdx.x >> 3;     // 0..127 row block
  const int ks = blockIdx.x & 7;      // 0..7   k-split (~XCD-local xT slice)
  const int n0 = rb * BM;
  const int k0 = ks * KRANGE;

  float th[S];
#pragma unroll
  for (int s = 0; s < S; ++s) th[s] = theta[s];

  const int wave = t >> 6, lane = t & 63;

  // raw T/a glob->LDS geometry: 1KB instr = 8 rows x 32 k
  const int grow = lane >> 3;         // 0..7
  const int gcol = (lane & 7) * 4;    // 0..28
  const size_t slice = (size_t)N * N;

  // qgen mapping: thread t -> row qr, cols qk..qk+3
  const int qr = t >> 3;              // 0..31
  const int qk = (t & 7) * 4;

  // MFMA tiling: wave w -> row-tile w>>1 (16 rows), feat-tiles (w&1)*4..+3
  const int rtile = wave >> 1;
  const int fbase = (wave & 1) * 4;

  f4 acc[4];
#pragma unroll
  for (int i = 0; i < 4; ++i) acc[i] = (f4)(0.f);

  auto stage_raw = [&](int c) {
    const size_t cb = (size_t)(k0 + c * BK) + gcol;
#pragma unroll
    for (int j = 0; j < 8; ++j) {
      const int i = wave * 8 + j;     // 0..31
      const int s = i >> 2;
      const int q4 = i & 3;
      const float* src = Ts + (size_t)s * slice +
                         (size_t)(n0 + q4 * 8 + grow) * N + cb;
      gload_lds16(src, (float*)&rawT[0][0][0] + i * 256);
    }
    {
      const float* src = a + (size_t)(n0 + wave * 8 + grow) * N + cb;
      gload_lds16(src, (float*)&rawA[0][0] + wave * 256);
    }
  };

  // stage xT tile: [128 f][32 k] bf16 = 8 KB = 8 instrs (2/wave)
  auto stage_x = [&](int c, int buf) {
    const uint8_t* xb = (const uint8_t*)xT;
    const size_t kbyte = (size_t)(k0 + c * BK) * 2;
#pragma unroll
    for (int j = 0; j < 2; ++j) {
      const int i = wave * 2 + j;     // 0..7, instr covers f rows i*16..+15
      const int fr = i * 16 + (lane >> 2);
      const uint8_t* src = xb + (size_t)fr * (N * 2) + kbyte + (lane & 3) * 16;
      gload_lds16(src, &xt_lds[buf][i * 16][0]);
    }
  };

  // q[qr][qk..+3] = bf16( a * sum_s th[s]*T[s] )
  auto qgen = [&]() {
    f4 av = *(const f4*)&rawA[qr][qk];
    f4 sum;
    {
      f4 tv = *(const f4*)&rawT[0][qr][qk];
#pragma unroll
      for (int j = 0; j < 4; ++j) sum[j] = th[0] * tv[j];
    }
#pragma unroll
    for (int s = 1; s < S; ++s) {
      f4 tv = *(const f4*)&rawT[s][qr][qk];
#pragma unroll
      for (int j = 0; j < 4; ++j) sum[j] = fmaf(th[s], tv[j], sum[j]);
    }
    us4 q;
#pragma unroll
    for (int j = 0; j < 4; ++j) q[j] = f2bf(av[j] * sum[j]);
    *(us4*)&q_lds[qr][qk] = q;      // ds_write_b64
  };

  auto compute = [&](int buf) {
    // A frag: q rows rtile*16..+15; lane -> row lane&15, k 8*(lane>>4)..+7
    const unsigned short* qb = &q_lds[rtile * 16][0];
    bf16x8 afrag = *(const bf16x8*)(qb + (lane & 15) * BK + (lane >> 4) * 8);
#pragma unroll
    for (int i = 0; i < 4; ++i) {
      const int ftile = fbase + i;
      const unsigned short* bb = &xt_lds[buf][ftile * 16][0];
      bf16x8 bfrag = *(const bf16x8*)(bb + (lane & 15) * BK + (lane >> 4) * 8);
      acc[i] = __builtin_amdgcn_mfma_f32_16x16x32_bf16(afrag, bfrag, acc[i],
                                                       0, 0, 0);
    }
  };

  // prologue
  stage_raw(0);
  stage_x(0, 0);
  vm_drain();
  bar_sync();
  qgen();
  bar_sync();

  for (int c = 0; c < NCH; ++c) {
    const int buf = c & 1;
    const bool more = (c + 1 < NCH);
    if (more) {
      stage_raw(c + 1);           // rawT slot free (qgen(c) already read it)
      stage_x(c + 1, buf ^ 1);
    }
    compute(buf);                  // MFMA on q[c] (x[buf]); overlaps gloads
    if (more) {
      vm_drain();                  // gloads covered by compute phase
      bar_sync();
      qgen();                      // build q[c+1]
      bar_sync();                  // publish q[c+1] + x[c+1]
    }
  }

  // write partials; C/D layout: col=lane&15, row=(lane>>4)*4+reg  (m89)
  const int crow = n0 + rtile * 16 + (lane >> 4) * 4;
  const int ccol = (lane & 15);
#pragma unroll
  for (int i = 0; i < 4; ++i) {
    const int fo = (fbase + i) * 16 + ccol;
#pragma unroll
    for (int r = 0; r < 4; ++r) {
      const size_t row = (size_t)(crow + r);
      if (USE_WS) {
        dst[((size_t)ks * N + row) * F + fo] = acc[i][r];
      } else {
        atomicAdd(dst + row * F + fo, acc[i][r]);
      }
    }
  }
}

// ---------------- kernel 2: (reduce) + PReLU + FC ----------------
template <bool USE_WS>
__global__ __launch_bounds__(256, 2) void ggd_fc(
    const float* __restrict__ W,      // [F][F] row-major [fo][fi]
    const float* __restrict__ bfc,    // [F]
    const float* __restrict__ alpha,  // [F]
    const float* __restrict__ src,    // ws [KSPLIT][N][F] or out [N][F]
    float* __restrict__ out)          // [N][F]
{
  __shared__ float p_lds[16 * F];     // 8 KB
  const int t  = threadIdx.x;
  const int n0 = blockIdx.x * 16;

  {
    const int lr = t >> 4, c8 = (t & 15) * 8;
    f4 v0, v1;
    if (USE_WS) {
      v0 = (f4)(0.f); v1 = (f4)(0.f);
#pragma unroll
      for (int ks = 0; ks < KSPLIT; ++ks) {
        const float* sp = src + ((size_t)ks * N + n0 + lr) * F + c8;
        v0 += *(const f4*)(sp);
        v1 += *(const f4*)(sp + 4);
      }
    } else {
      const float* ip = src + (size_t)(n0 + lr) * F + c8;
      v0 = *(const f4*)(ip);
      v1 = *(const f4*)(ip + 4);
    }
    f4 a0 = *(const f4*)(alpha + c8);
    f4 a1 = *(const f4*)(alpha + c8 + 4);
#pragma unroll
    for (int j = 0; j < 4; ++j) {
      v0[j] = v0[j] >= 0.f ? v0[j] : a0[j] * v0[j];
      v1[j] = v1[j] >= 0.f ? v1[j] : a1[j] * v1[j];
    }
    *(f4*)&p_lds[lr * F + c8]     = v0;
    *(f4*)&p_lds[lr * F + c8 + 4] = v1;
  }
  __syncthreads();

  const int r2  = t >> 5;             // 0..7
  const int fo0 = (t & 31) * 4;
  f4 accA = *(const f4*)(bfc + fo0);
  f4 accB = accA;
#pragma unroll 4
  for (int fi4 = 0; fi4 < F / 4; ++fi4) {
    f4 pA = *(const f4*)&p_lds[r2 * F + fi4 * 4];
    f4 pB = *(const f4*)&p_lds[(r2 + 8) * F + fi4 * 4];
#pragma unroll
    for (int e = 0; e < 4; ++e) {
      f4 wv = *(const f4*)(W + (size_t)(fo0 + e) * F + fi4 * 4);
      accA[e] = fmaf(pA[0], wv[0], fmaf(pA[1], wv[1],
                fmaf(pA[2], wv[2], fmaf(pA[3], wv[3], accA[e]))));
      accB[e] = fmaf(pB[0], wv[0], fmaf(pB[1], wv[1],
                fmaf(pB[2], wv[2], fmaf(pB[3], wv[3], accB[e]))));
    }
  }
  *(f4*)(out + (size_t)(n0 + r2) * F + fo0)     = accA;
  *(f4*)(out + (size_t)(n0 + r2 + 8) * F + fo0) = accB;
}

extern "C" void kernel_launch(void* const* d_in, const int* in_sizes, int n_in,
                              void* d_out, int out_size, void* d_ws, size_t ws_size,
                              hipStream_t stream) {
  const float* theta = (const float*)d_in[0];
  const float* Ts    = (const float*)d_in[1];
  const float* x     = (const float*)d_in[2];
  const float* a     = (const float*)d_in[3];
  const float* W     = (const float*)d_in[4];
  const float* bfc   = (const float*)d_in[5];
  const float* alpha = (const float*)d_in[6];
  float* out = (float*)d_out;

  const size_t part_bytes = (size_t)KSPLIT * N * F * sizeof(float);  // 16.8 MB
  const size_t xt_bytes   = (size_t)N * F * 2;                       // 1 MB
  if (ws_size >= part_bytes + xt_bytes && d_ws != nullptr) {
    float* parts = (float*)d_ws;
    unsigned short* xT = (unsigned short*)((char*)d_ws + part_bytes);
    ggd_xt<<<dim3(N / 64), dim3(256), 0, stream>>>(x, xT);
    ggd_diffuse<true><<<dim3((N / BM) * KSPLIT), dim3(NT), 0, stream>>>(
        theta, Ts, xT, a, parts);
    ggd_fc<true><<<dim3(N / 16), dim3(256), 0, stream>>>(
        W, bfc, alpha, parts, out);
  } else {
    // fallback: atomic accumulation into out (needs only 1 MB ws for xT)
    unsigned short* xT = (unsigned short*)d_ws;
    hipMemsetAsync(out, 0, (size_t)out_size * sizeof(float), stream);
    ggd_xt<<<dim3(N / 64), dim3(256), 0, stream>>>(x, xT);
    ggd_diffuse<false><<<dim3((N / BM) * KSPLIT), dim3(NT), 0, stream>>>(
        theta, Ts, xT, a, out);
    ggd_fc<false><<<dim3(N / 16), dim3(256), 0, stream>>>(
        W, bfc, alpha, out, out);
  }
}